// Round 1
// baseline (9654.198 us; speedup 1.0000x reference)
//
#include <hip/hip_runtime.h>

#define N_NODES 1024
#define DC 64
#define DM 128
#define FREQ 42
#define TREC 41
#define SEG 8
#define NB 8
#define MAXK 11
#define NSTEP 12
#define TSTR 65536  // 1024*64 per-t stride (floats)
#define ALPHA_C 0.05f
#define BETA_C 0.95f

// ---------------- adjacency prep ----------------
__global__ void transpose_k(const float* __restrict__ in, float* __restrict__ out) {
  __shared__ float tile[32][33];
  int bx = blockIdx.x * 32, by = blockIdx.y * 32;
  int x = threadIdx.x, y = threadIdx.y;
#pragma unroll
  for (int j = 0; j < 32; j += 8) tile[y + j][x] = in[(size_t)(by + y + j) * N_NODES + bx + x];
  __syncthreads();
#pragma unroll
  for (int j = 0; j < 32; j += 8) out[(size_t)(bx + y + j) * N_NODES + by + x] = tile[x][y + j];
}

__global__ void rowsum_k(const float* __restrict__ m, float* __restrict__ sums) {
  int v = blockIdx.x;
  float s = 0.f;
  for (int n = threadIdx.x; n < N_NODES; n += 256) s += m[(size_t)v * N_NODES + n];
  __shared__ float red[256];
  red[threadIdx.x] = s;
  __syncthreads();
  for (int w = 128; w > 0; w >>= 1) {
    if (threadIdx.x < w) red[threadIdx.x] += red[threadIdx.x + w];
    __syncthreads();
  }
  if (threadIdx.x == 0) sums[v] = red[0] + 1.0f;  // +1 for identity diag
}

__global__ void norm_k(const float* __restrict__ adj, const float* __restrict__ adjT,
                       const float* __restrict__ rs, const float* __restrict__ cs,
                       float* __restrict__ a1, float* __restrict__ a2) {
  int v = blockIdx.x & (N_NODES - 1);
  bool second = blockIdx.x >= N_NODES;
  const float* src = second ? adjT : adj;
  float inv = 1.0f / (second ? cs[v] : rs[v]);
  float* dst = second ? a2 : a1;
  for (int n = threadIdx.x; n < N_NODES; n += 256) {
    float val = src[(size_t)v * N_NODES + n] + (n == v ? 1.0f : 0.0f);
    dst[(size_t)v * N_NODES + n] = val * inv;
  }
}

// ---------------- combined inception weights ----------------
// Wc[dtIdx][di][do], dtIdx = dt+5, dt in [-5,5]; Wc[dtIdx*4096 + di*64 + do]
__global__ void combine_w_k(const float* w0, const float* w1, const float* w2,
                            const float* w3, const float* w4, const float* w5,
                            const float* b0, const float* b1, const float* b2,
                            const float* b3, const float* b4, const float* b5,
                            float* __restrict__ Wc, float* __restrict__ bsum) {
  int idx = blockIdx.x * 256 + threadIdx.x;
  if (idx < MAXK * DC * DC) {
    int dtI = idx >> 12;
    int di = (idx >> 6) & 63;
    int dout = idx & 63;
    int d = dtI - 5;
    int ad = d < 0 ? -d : d;
    const float* ws[6] = {w0, w1, w2, w3, w4, w5};
    float s = 0.f;
    for (int i = 0; i < 6; ++i) {
      if (i >= ad) {
        int K = 2 * i + 1;
        s += ws[i][((size_t)dout * DC + di) * K + (d + i)];
      }
    }
    Wc[idx] = s;
  }
  if (idx < DC) bsum[idx] = b0[idx] + b1[idx] + b2[idx] + b3[idx] + b4[idx] + b5[idx];
}

// ---------------- encoder: (b,f,n): seg[8] -> 128 relu -> 64 ----------------
__global__ void encoder_k(const float* __restrict__ x, const float* __restrict__ w1,
                          const float* __restrict__ b1, const float* __restrict__ w2,
                          const float* __restrict__ b2, float* __restrict__ res) {
  int blk = blockIdx.x;            // NB*FREQ*256 blocks
  int nb = (blk & 255) * 4;
  int bf = blk >> 8;               // 0..NB*FREQ-1
  int f = bf % FREQ;
  int b = bf / FREQ;
  int g = threadIdx.x >> 6;
  int lane = threadIdx.x & 63;
  int n = nb + g;
  __shared__ float ss[4][SEG];
  __shared__ float hs[4][DM];
  if (lane < SEG) ss[g][lane] = x[(size_t)(b * 336 + f * SEG + lane) * N_NODES + n];
  __syncthreads();
#pragma unroll
  for (int half = 0; half < 2; ++half) {
    int j = lane + half * 64;
    float acc = b1[j];
#pragma unroll
    for (int k = 0; k < SEG; ++k) acc = fmaf(ss[g][k], w1[k * DM + j], acc);
    hs[g][j] = fmaxf(acc, 0.0f);
  }
  __syncthreads();
  float acc = b2[lane];
#pragma unroll 16
  for (int j = 0; j < DM; ++j) acc = fmaf(hs[g][j], w2[j * DC + lane], acc);
  res[((size_t)(b * FREQ + f) * N_NODES + n) * DC + lane] = acc;
}

// ---------------- shared GEMM tile helpers ----------------
__device__ __forceinline__ void load_tiles(float* As, float* Hs, const float* aSrc,
                                           size_t aRowStride, const float* hSrc, int tid) {
#pragma unroll
  for (int i = 0; i < 16; ++i) {
    int idx = tid + i * 256;
    int rr = idx >> 6, cc = idx & 63;
    As[rr * 65 + cc] = aSrc[(size_t)rr * aRowStride + cc];
    Hs[idx] = hSrc[idx];
  }
}

__device__ __forceinline__ void gemm_tile(const float* As, const float* Hs, int r, int cq,
                                          float acc[16]) {
#pragma unroll
  for (int k = 0; k < 64; ++k) {
    float a = As[r * 65 + k];
#pragma unroll
    for (int q = 0; q < 4; ++q) {
      const float4 w = *reinterpret_cast<const float4*>(&Hs[k * 64 + cq + q * 4]);
      acc[q * 4 + 0] = fmaf(a, w.x, acc[q * 4 + 0]);
      acc[q * 4 + 1] = fmaf(a, w.y, acc[q * 4 + 1]);
      acc[q * 4 + 2] = fmaf(a, w.z, acc[q * 4 + 2]);
      acc[q * 4 + 3] = fmaf(a, w.w, acc[q * 4 + 3]);
    }
  }
}

// ---------------- inception conv (rec branch), T=41 ----------------
__global__ void __launch_bounds__(256) incep_rec_k(const float* __restrict__ xin,
                                                   const float* __restrict__ Wc,
                                                   const float* __restrict__ bsum,
                                                   float* __restrict__ xc) {
  int t = blockIdx.y;
  int v0 = blockIdx.x * 64;
  __shared__ float As[64 * 65];
  __shared__ float Hs[64 * 64];
  int tid = threadIdx.x;
  int r = tid >> 2, cq = (tid & 3) << 4;
  float acc[16];
#pragma unroll
  for (int q = 0; q < 16; ++q) acc[q] = 0.f;
  for (int dtI = 0; dtI < MAXK; ++dtI) {
    int ts = t + dtI - 5;
    if (ts < 0 || ts >= TREC) continue;
    load_tiles(As, Hs, xin + (size_t)ts * TSTR + (size_t)v0 * DC, DC, Wc + dtI * 4096, tid);
    __syncthreads();
    gemm_tile(As, Hs, r, cq, acc);
    __syncthreads();
  }
  float* dst = xc + (size_t)t * TSTR + (size_t)(v0 + r) * DC;
#pragma unroll
  for (int q = 0; q < 4; ++q) {
    int c = cq + q * 4;
    float4 o;
    o.x = (acc[q * 4 + 0] + bsum[c + 0]) * (1.f / 6.f);
    o.y = (acc[q * 4 + 1] + bsum[c + 1]) * (1.f / 6.f);
    o.z = (acc[q * 4 + 2] + bsum[c + 2]) * (1.f / 6.f);
    o.w = (acc[q * 4 + 3] + bsum[c + 3]) * (1.f / 6.f);
    *reinterpret_cast<float4*>(&dst[c]) = o;
  }
}

// ---------------- inception conv (AR, last position only) ----------------
__global__ void __launch_bounds__(256) incep_ar_k(const float* __restrict__ cur, int start,
                                                  const float* __restrict__ Wc,
                                                  const float* __restrict__ bsum,
                                                  float* __restrict__ y) {
  int b = blockIdx.y;
  int v0 = blockIdx.x * 64;
  __shared__ float As[64 * 65];
  __shared__ float Hs[64 * 64];
  int tid = threadIdx.x;
  int r = tid >> 2, cq = (tid & 3) << 4;
  float acc[16];
#pragma unroll
  for (int q = 0; q < 16; ++q) acc[q] = 0.f;
  for (int j = 0; j < 6; ++j) {  // taps dt=-5..0 -> dtIdx = j
    int slot = (start + 5 + j) % MAXK;
    const float* src = cur + ((size_t)b * MAXK + slot) * TSTR + (size_t)v0 * DC;
    load_tiles(As, Hs, src, DC, Wc + j * 4096, tid);
    __syncthreads();
    gemm_tile(As, Hs, r, cq, acc);
    __syncthreads();
  }
  float* dst = y + (size_t)b * TSTR + (size_t)(v0 + r) * DC;
#pragma unroll
  for (int q = 0; q < 4; ++q) {
    int c = cq + q * 4;
    float4 o;
    o.x = (acc[q * 4 + 0] + bsum[c + 0]) * (1.f / 6.f);
    o.y = (acc[q * 4 + 1] + bsum[c + 1]) * (1.f / 6.f);
    o.z = (acc[q * 4 + 2] + bsum[c + 2]) * (1.f / 6.f);
    o.w = (acc[q * 4 + 3] + bsum[c + 3]) * (1.f / 6.f);
    *reinterpret_cast<float4*>(&dst[c]) = o;
  }
}

// ---------------- mixprop propagation: Hout = 0.05*X + 0.95*(A @ Hin) ----------------
__global__ void __launch_bounds__(256) prop_k(const float* __restrict__ A,
                                              const float* __restrict__ Hin,
                                              const float* __restrict__ X,
                                              float* __restrict__ Hout, size_t hinStride,
                                              size_t xStride, size_t outStride) {
  int t = blockIdx.y;
  int v0 = blockIdx.x * 64;
  const float* Ht = Hin + (size_t)t * hinStride;
  __shared__ float As[64 * 65];
  __shared__ float Hs[64 * 64];
  int tid = threadIdx.x;
  int r = tid >> 2, cq = (tid & 3) << 4;
  float acc[16];
#pragma unroll
  for (int q = 0; q < 16; ++q) acc[q] = 0.f;
  for (int k0 = 0; k0 < N_NODES; k0 += 64) {
    load_tiles(As, Hs, A + (size_t)v0 * N_NODES + k0, N_NODES, Ht + (size_t)k0 * DC, tid);
    __syncthreads();
    gemm_tile(As, Hs, r, cq, acc);
    __syncthreads();
  }
  const float* Xt = X + (size_t)t * xStride + (size_t)(v0 + r) * DC;
  float* Ot = Hout + (size_t)t * outStride + (size_t)(v0 + r) * DC;
#pragma unroll
  for (int q = 0; q < 4; ++q) {
    int c = cq + q * 4;
    float4 xv = *reinterpret_cast<const float4*>(&Xt[c]);
    float4 o;
    o.x = ALPHA_C * xv.x + BETA_C * acc[q * 4 + 0];
    o.y = ALPHA_C * xv.y + BETA_C * acc[q * 4 + 1];
    o.z = ALPHA_C * xv.z + BETA_C * acc[q * 4 + 2];
    o.w = ALPHA_C * xv.w + BETA_C * acc[q * 4 + 3];
    *reinterpret_cast<float4*>(&Ot[c]) = o;
  }
}

// ---------------- mixprop output: out (=|+=) X? + [h0,h1,h2]@gw + gb ----------------
__global__ void __launch_bounds__(256) gwacc_k(const float* __restrict__ h0,
                                               const float* __restrict__ h1,
                                               const float* __restrict__ h2, size_t hStride,
                                               const float* __restrict__ gw,
                                               const float* __restrict__ gb,
                                               const float* __restrict__ X, size_t xStride,
                                               float* __restrict__ out, size_t outStride,
                                               int initF) {
  int t = blockIdx.y;
  int v0 = blockIdx.x * 64;
  __shared__ float As[64 * 65];
  __shared__ float Hs[64 * 64];
  int tid = threadIdx.x;
  int r = tid >> 2, cq = (tid & 3) << 4;
  float acc[16];
#pragma unroll
  for (int q = 0; q < 16; ++q) acc[q] = 0.f;
  const float* hp[3];
  hp[0] = h0 + (size_t)t * hStride;
  hp[1] = h1 + (size_t)t * hStride;
  hp[2] = h2 + (size_t)t * hStride;
  for (int p = 0; p < 3; ++p) {
    load_tiles(As, Hs, hp[p] + (size_t)v0 * DC, DC, gw + (size_t)p * 64 * DC, tid);
    __syncthreads();
    gemm_tile(As, Hs, r, cq, acc);
    __syncthreads();
  }
  float* O = out + (size_t)t * outStride + (size_t)(v0 + r) * DC;
  const float* Xt = X + (size_t)t * xStride + (size_t)(v0 + r) * DC;
#pragma unroll
  for (int q = 0; q < 4; ++q) {
    int c = cq + q * 4;
    float4 base = initF ? *reinterpret_cast<const float4*>(&Xt[c])
                        : *reinterpret_cast<const float4*>(&O[c]);
    float4 o;
    o.x = base.x + acc[q * 4 + 0] + gb[c + 0];
    o.y = base.y + acc[q * 4 + 1] + gb[c + 1];
    o.z = base.z + acc[q * 4 + 2] + gb[c + 2];
    o.w = base.w + acc[q * 4 + 3] + gb[c + 3];
    *reinterpret_cast<float4*>(&O[c]) = o;
  }
}

// ---------------- cur ring init: cur = res[:, 31:42] ----------------
__global__ void curinit_k(const float* __restrict__ res, float* __restrict__ cur) {
  size_t idx = (size_t)blockIdx.x * 256 + threadIdx.x;
  const size_t per_b = (size_t)MAXK * TSTR;
  if (idx < (size_t)NB * per_b) {
    size_t b = idx / per_b, rem = idx % per_b;
    cur[idx] = res[b * ((size_t)FREQ * TSTR) + (size_t)31 * TSTR + rem];
  }
}

// ---------------- decoder (rec branch, per-b) ----------------
__global__ void dec_rec_k(const float* __restrict__ resB, const float* __restrict__ accB,
                          const float* __restrict__ dw1, const float* __restrict__ db1,
                          const float* __restrict__ dw2, const float* __restrict__ db2,
                          float* __restrict__ outB) {
  int blk = blockIdx.x;  // FREQ*256
  int f = blk >> 8;
  int nb = (blk & 255) * 4;
  int g = threadIdx.x >> 6, lane = threadIdx.x & 63;
  int n = nb + g;
  const float* in = (f == 0 ? resB : accB + (size_t)(f - 1) * TSTR) + (size_t)n * DC;
  __shared__ float ins[4][DC];
  __shared__ float hs[4][DM];
  ins[g][lane] = in[lane];
  __syncthreads();
#pragma unroll
  for (int half = 0; half < 2; ++half) {
    int j = lane + half * 64;
    float acc = db1[j];
#pragma unroll 16
    for (int d = 0; d < DC; ++d) acc = fmaf(ins[g][d], dw1[d * DM + j], acc);
    hs[g][j] = fmaxf(acc, 0.f);
  }
  __syncthreads();
  if (lane < SEG) {
    float acc = db2[lane];
#pragma unroll 16
    for (int j = 0; j < DM; ++j) acc = fmaf(hs[g][j], dw2[j * SEG + lane], acc);
    outB[(size_t)(f * SEG + lane) * N_NODES + n] = acc;
  }
}

// ---------------- decoder (pred, one AR step) ----------------
__global__ void dec_pred_k(const float* __restrict__ curSlot, const float* __restrict__ dw1,
                           const float* __restrict__ db1, const float* __restrict__ dw2,
                           const float* __restrict__ db2, float* __restrict__ predBase) {
  int blk = blockIdx.x;  // NB*256
  int b = blk >> 8;
  int nb = (blk & 255) * 4;
  int g = threadIdx.x >> 6, lane = threadIdx.x & 63;
  int n = nb + g;
  const float* in = curSlot + (size_t)b * (MAXK * (size_t)TSTR) + (size_t)n * DC;
  __shared__ float ins[4][DC];
  __shared__ float hs[4][DM];
  ins[g][lane] = in[lane];
  __syncthreads();
#pragma unroll
  for (int half = 0; half < 2; ++half) {
    int j = lane + half * 64;
    float acc = db1[j];
#pragma unroll 16
    for (int d = 0; d < DC; ++d) acc = fmaf(ins[g][d], dw1[d * DM + j], acc);
    hs[g][j] = fmaxf(acc, 0.f);
  }
  __syncthreads();
  if (lane < SEG) {
    float acc = db2[lane];
#pragma unroll 16
    for (int j = 0; j < DM; ++j) acc = fmaf(hs[g][j], dw2[j * SEG + lane], acc);
    predBase[(size_t)b * 98304 + (size_t)n * SEG + lane] = acc;
  }
}

// ---------------- host launch ----------------
extern "C" void kernel_launch(void* const* d_in, const int* in_sizes, int n_in, void* d_out,
                              int out_size, void* d_ws, size_t ws_size, hipStream_t stream) {
  const float* x_diff = (const float*)d_in[0];
  const float* adj = (const float*)d_in[1];
  const float* enc_w1 = (const float*)d_in[2];
  const float* enc_b1 = (const float*)d_in[3];
  const float* enc_w2 = (const float*)d_in[4];
  const float* enc_b2 = (const float*)d_in[5];
  const float* dec_w1 = (const float*)d_in[6];
  const float* dec_b1 = (const float*)d_in[7];
  const float* dec_w2 = (const float*)d_in[8];
  const float* dec_b2 = (const float*)d_in[9];
  const float* g1_w = (const float*)d_in[10];
  const float* g1_b = (const float*)d_in[11];
  const float* g2_w = (const float*)d_in[12];
  const float* g2_b = (const float*)d_in[13];
  const float* cw[6];
  const float* cb[6];
  for (int i = 0; i < 6; ++i) {
    cw[i] = (const float*)d_in[14 + 2 * i];
    cb[i] = (const float*)d_in[15 + 2 * i];
  }

  float* w = (float*)d_ws;
  size_t off = 0;
#define TAKE(name, cnt) \
  float* name = w + off; \
  off += (((size_t)(cnt)) + 255) & ~(size_t)255;
  TAKE(a1, 1048576)
  TAKE(a2, 1048576)
  TAKE(adjT, 1048576)
  TAKE(rowsum, 1024)
  TAKE(colsum, 1024)
  TAKE(Wc, MAXK * DC * DC)
  TAKE(bsum, DC)
  TAKE(res, (size_t)NB * FREQ * TSTR)
  TAKE(xcB, (size_t)TREC * TSTR)
  TAKE(hA, (size_t)TREC * TSTR)
  TAKE(hB, (size_t)TREC * TSTR)
  TAKE(accB, (size_t)TREC * TSTR)
  TAKE(cur, (size_t)NB * MAXK * TSTR)
  TAKE(yb, (size_t)NB * TSTR)
  TAKE(hAy, (size_t)NB * TSTR)
  TAKE(hBy, (size_t)NB * TSTR)
#undef TAKE

  float* outF = (float*)d_out;
  float* outRec = outF;                        // 8*336*1024
  float* outPred = outF + (size_t)2752512;     // 8*96*1024

  transpose_k<<<dim3(32, 32), dim3(32, 8), 0, stream>>>(adj, adjT);
  rowsum_k<<<1024, 256, 0, stream>>>(adj, rowsum);
  rowsum_k<<<1024, 256, 0, stream>>>(adjT, colsum);
  norm_k<<<2048, 256, 0, stream>>>(adj, adjT, rowsum, colsum, a1, a2);
  combine_w_k<<<(MAXK * DC * DC + 255) / 256, 256, 0, stream>>>(
      cw[0], cw[1], cw[2], cw[3], cw[4], cw[5], cb[0], cb[1], cb[2], cb[3], cb[4], cb[5], Wc,
      bsum);
  encoder_k<<<NB * FREQ * 256, 256, 0, stream>>>(x_diff, enc_w1, enc_b1, enc_w2, enc_b2, res);
  curinit_k<<<(int)(((size_t)NB * MAXK * TSTR + 255) / 256), 256, 0, stream>>>(res, cur);

  // ---- reconstruction branch (chunked per batch element) ----
  for (int b = 0; b < NB; ++b) {
    const float* xin = res + (size_t)b * FREQ * TSTR;  // first TREC slices used
    incep_rec_k<<<dim3(16, TREC), 256, 0, stream>>>(xin, Wc, bsum, xcB);
    for (int a = 0; a < 2; ++a) {
      const float* A = a ? a2 : a1;
      const float* gwp = a ? g2_w : g1_w;
      const float* gbp = a ? g2_b : g1_b;
      prop_k<<<dim3(16, TREC), 256, 0, stream>>>(A, xcB, xcB, hA, TSTR, TSTR, TSTR);
      prop_k<<<dim3(16, TREC), 256, 0, stream>>>(A, hA, xcB, hB, TSTR, TSTR, TSTR);
      gwacc_k<<<dim3(16, TREC), 256, 0, stream>>>(xcB, hA, hB, TSTR, gwp, gbp, xin, TSTR, accB,
                                                  TSTR, a == 0 ? 1 : 0);
    }
    dec_rec_k<<<FREQ * 256, 256, 0, stream>>>(xin, accB, dec_w1, dec_b1, dec_w2, dec_b2,
                                              outRec + (size_t)b * 344064);
  }

  // ---- autoregressive branch ----
  for (int s = 0; s < NSTEP; ++s) {
    int start = s;
    int slot_r = (start + 10) % MAXK;
    int slot_w = start % MAXK;
    incep_ar_k<<<dim3(16, NB), 256, 0, stream>>>(cur, start, Wc, bsum, yb);
    for (int a = 0; a < 2; ++a) {
      const float* A = a ? a2 : a1;
      const float* gwp = a ? g2_w : g1_w;
      const float* gbp = a ? g2_b : g1_b;
      prop_k<<<dim3(16, NB), 256, 0, stream>>>(A, yb, yb, hAy, TSTR, TSTR, TSTR);
      prop_k<<<dim3(16, NB), 256, 0, stream>>>(A, hAy, yb, hBy, TSTR, TSTR, TSTR);
      gwacc_k<<<dim3(16, NB), 256, 0, stream>>>(
          yb, hAy, hBy, TSTR, gwp, gbp, cur + (size_t)slot_r * TSTR, (size_t)MAXK * TSTR,
          cur + (size_t)slot_w * TSTR, (size_t)MAXK * TSTR, a == 0 ? 1 : 0);
    }
    dec_pred_k<<<NB * 256, 256, 0, stream>>>(cur + (size_t)slot_w * TSTR, dec_w1, dec_b1,
                                             dec_w2, dec_b2, outPred + (size_t)s * 8192);
  }
}

// Round 2
// 2607.449 us; speedup vs baseline: 3.7025x; 3.7025x over previous
//
#include <hip/hip_runtime.h>

typedef __bf16 bf16;
typedef __bf16 bf16x8 __attribute__((ext_vector_type(8)));
typedef float f32x4 __attribute__((ext_vector_type(4)));

#define N_NODES 1024
#define DC 64
#define FREQ 42
#define TREC 41
#define NB 8
#define MAXK 11
#define NSTEP 12
#define SLICE 65536  // 1024*64

struct Ptr6 { const bf16* p[6]; };

// ---------------- adjacency prep ----------------
__global__ void transpose_k(const float* __restrict__ in, float* __restrict__ out) {
  __shared__ float tile[32][33];
  int bx = blockIdx.x * 32, by = blockIdx.y * 32;
  int x = threadIdx.x, y = threadIdx.y;
#pragma unroll
  for (int j = 0; j < 32; j += 8) tile[y + j][x] = in[(size_t)(by + y + j) * N_NODES + bx + x];
  __syncthreads();
#pragma unroll
  for (int j = 0; j < 32; j += 8) out[(size_t)(bx + y + j) * N_NODES + by + x] = tile[x][y + j];
}

__global__ void rowsum_k(const float* __restrict__ m, float* __restrict__ sums) {
  int v = blockIdx.x;
  float s = 0.f;
  for (int n = threadIdx.x; n < N_NODES; n += 256) s += m[(size_t)v * N_NODES + n];
  __shared__ float red[256];
  red[threadIdx.x] = s;
  __syncthreads();
  for (int w = 128; w > 0; w >>= 1) {
    if (threadIdx.x < w) red[threadIdx.x] += red[threadIdx.x + w];
    __syncthreads();
  }
  if (threadIdx.x == 0) sums[v] = red[0] + 1.0f;
}

__global__ void norm_k(const float* __restrict__ adj, const float* __restrict__ adjT,
                       const float* __restrict__ rs, const float* __restrict__ cs,
                       bf16* __restrict__ a1, bf16* __restrict__ a2) {
  int v = blockIdx.x & (N_NODES - 1);
  bool second = blockIdx.x >= N_NODES;
  const float* src = second ? adjT : adj;
  float inv = 1.0f / (second ? cs[v] : rs[v]);
  bf16* dst = second ? a2 : a1;
  for (int n = threadIdx.x; n < N_NODES; n += 256) {
    float val = src[(size_t)v * N_NODES + n] + (n == v ? 1.0f : 0.0f);
    dst[(size_t)v * N_NODES + n] = (bf16)(val * inv);
  }
}

// ---------------- combined inception weights: Wc[dt][dout][di] bf16 ----------------
__global__ void combine_w_k(const float* w0, const float* w1, const float* w2, const float* w3,
                            const float* w4, const float* w5, const float* b0, const float* b1,
                            const float* b2, const float* b3, const float* b4, const float* b5,
                            bf16* __restrict__ Wc, float* __restrict__ bsum) {
  int idx = blockIdx.x * 256 + threadIdx.x;
  if (idx < MAXK * 4096) {
    int dtI = idx >> 12;
    int dout = (idx >> 6) & 63;
    int di = idx & 63;
    int d = dtI - 5;
    int ad = d < 0 ? -d : d;
    const float* ws[6] = {w0, w1, w2, w3, w4, w5};
    float s = 0.f;
    for (int i = 0; i < 6; ++i)
      if (i >= ad) {
        int K = 2 * i + 1;
        s += ws[i][((size_t)dout * 64 + di) * K + (d + i)];
      }
    Wc[idx] = (bf16)s;
  }
  if (idx < 64) bsum[idx] = b0[idx] + b1[idx] + b2[idx] + b3[idx] + b4[idx] + b5[idx];
}

// ---------------- gwT[dout][384] bf16 (g1 cols 0-191, g2 cols 192-383) ----------------
__global__ void gwt_k(const float* __restrict__ g1w, const float* __restrict__ g2w,
                      const float* __restrict__ g1b, const float* __restrict__ g2b,
                      bf16* __restrict__ gwT, float* __restrict__ gbsum) {
  int idx = blockIdx.x * 256 + threadIdx.x;
  if (idx < 64 * 384) {
    int dd = idx / 384, k = idx % 384;
    float v = k < 192 ? g1w[(size_t)k * 64 + dd] : g2w[(size_t)(k - 192) * 64 + dd];
    gwT[idx] = (bf16)v;
  }
  if (idx < 64) gbsum[idx] = g1b[idx] + g2b[idx];
}

// ---------------- encoder: writes resb bf16 node-major [b*42+f][v][64] ----------------
__global__ __launch_bounds__(256) void encoder_k(const float* __restrict__ x,
                                                 const float* __restrict__ w1,
                                                 const float* __restrict__ b1,
                                                 const float* __restrict__ w2,
                                                 const float* __restrict__ b2,
                                                 bf16* __restrict__ resb) {
  __shared__ __align__(16) float xs[8][64];
  __shared__ __align__(16) float w1s[8][128];
  __shared__ __align__(16) float w2s[128 * 64];
  __shared__ bf16 hs[64 * 132];
  __shared__ float b1s[128], b2s[64];
  int t = threadIdx.x;
  int v0 = blockIdx.x * 64;
  int bfp = blockIdx.y;
  int b = bfp / FREQ, f = bfp % FREQ;
#pragma unroll
  for (int i = 0; i < 2; ++i) {
    int q = t + i * 256;
    xs[q >> 6][q & 63] = x[(size_t)(b * 336 + f * 8 + (q >> 6)) * 1024 + v0 + (q & 63)];
  }
#pragma unroll
  for (int i = 0; i < 4; ++i) {
    int q = t + i * 256;
    w1s[q >> 7][q & 127] = w1[q];
  }
#pragma unroll
  for (int i = 0; i < 32; ++i) w2s[t + i * 256] = w2[t + i * 256];
  if (t < 128) b1s[t] = b1[t];
  if (t < 64) b2s[t] = b2[t];
  __syncthreads();
  {
    int n = t & 63, jc = (t >> 6) * 32;
    for (int jj = 0; jj < 32; ++jj) {
      int j = jc + jj;
      float a = b1s[j];
#pragma unroll
      for (int k = 0; k < 8; ++k) a = fmaf(xs[k][n], w1s[k][j], a);
      hs[n * 132 + j] = (bf16)fmaxf(a, 0.f);
    }
  }
  __syncthreads();
  {
    int n = t >> 2, dc = (t & 3) * 16;
    float o[16];
#pragma unroll
    for (int i = 0; i < 16; ++i) o[i] = b2s[dc + i];
    for (int j = 0; j < 128; ++j) {
      float h = (float)hs[n * 132 + j];
      const float4* wrow = (const float4*)&w2s[j * 64 + dc];
#pragma unroll
      for (int q = 0; q < 4; ++q) {
        float4 wv = wrow[q];
        o[q * 4 + 0] = fmaf(h, wv.x, o[q * 4 + 0]);
        o[q * 4 + 1] = fmaf(h, wv.y, o[q * 4 + 1]);
        o[q * 4 + 2] = fmaf(h, wv.z, o[q * 4 + 2]);
        o[q * 4 + 3] = fmaf(h, wv.w, o[q * 4 + 3]);
      }
    }
    bf16 ob[16];
#pragma unroll
    for (int i = 0; i < 16; ++i) ob[i] = (bf16)o[i];
    bf16* dst = &resb[(size_t)(b * FREQ + f) * SLICE + (size_t)(v0 + n) * 64 + dc];
    *(uint4*)dst = ((uint4*)ob)[0];
    *(uint4*)(dst + 8) = ((uint4*)ob)[1];
  }
}

// ---------------- cur init ----------------
__global__ void curinit_k(const bf16* __restrict__ resb, float* __restrict__ cur,
                          bf16* __restrict__ curb) {
  size_t idx = (size_t)blockIdx.x * 256 + threadIdx.x;
  const size_t per_b = (size_t)MAXK * SLICE;
  if (idx < (size_t)NB * per_b) {
    size_t b = idx / per_b, rem = idx % per_b;
    bf16 v = resb[b * ((size_t)FREQ * SLICE) + (size_t)31 * SLICE + rem];
    cur[idx] = (float)v;
    curb[idx] = v;
  }
}

// ---------------- MFMA tile helpers ----------------
__device__ __forceinline__ void stageA(bf16* lds_a, const bf16* src, int rowStride, int tid) {
#pragma unroll
  for (int i = 0; i < 8; ++i) {
    int q = tid + i * 256;
    int r = q >> 3, c = (q & 7) << 3;
    *(uint4*)&lds_a[r * 72 + c] = *(const uint4*)&src[(size_t)r * rowStride + c];
  }
}
__device__ __forceinline__ void stageB(bf16* lds_b, const bf16* src, int rowStride, int tid) {
#pragma unroll
  for (int i = 0; i < 2; ++i) {
    int q = tid + i * 256;
    int r = q >> 3, c = (q & 7) << 3;
    *(uint4*)&lds_b[r * 72 + c] = *(const uint4*)&src[(size_t)r * rowStride + c];
  }
}
__device__ __forceinline__ void mfma64(const bf16* lds_a, const bf16* lds_b, int wid, int lane,
                                       f32x4 acc[4][4]) {
  int lr = lane & 15, lg = lane >> 4;
#pragma unroll
  for (int h = 0; h < 2; ++h) {
    bf16x8 af[4], bfr[4];
#pragma unroll
    for (int mi = 0; mi < 4; ++mi)
      af[mi] = *(const bf16x8*)&lds_a[(wid * 64 + mi * 16 + lr) * 72 + h * 32 + lg * 8];
#pragma unroll
    for (int ni = 0; ni < 4; ++ni)
      bfr[ni] = *(const bf16x8*)&lds_b[(ni * 16 + lr) * 72 + h * 32 + lg * 8];
#pragma unroll
    for (int mi = 0; mi < 4; ++mi)
#pragma unroll
      for (int ni = 0; ni < 4; ++ni)
        acc[mi][ni] =
            __builtin_amdgcn_mfma_f32_16x16x32_bf16(af[mi], bfr[ni], acc[mi][ni], 0, 0, 0);
  }
}

// ---------------- inception (rec): xc = (conv(res) + bsum)/6 ----------------
__global__ __launch_bounds__(256) void incep_k(const bf16* __restrict__ resb, int b0,
                                               const bf16* __restrict__ Wc,
                                               const float* __restrict__ bsum,
                                               bf16* __restrict__ xcN, bf16* __restrict__ xcF) {
  __shared__ __align__(16) bf16 lds_a[256 * 72];
  __shared__ __align__(16) bf16 lds_b[64 * 72];
  int tid = threadIdx.x, wid = tid >> 6, lane = tid & 63;
  int v0 = blockIdx.x * 256;
  int sl = blockIdx.y;
  int b = b0 + sl / TREC, tt = sl % TREC;
  f32x4 acc[4][4] = {};
  for (int dt = 0; dt < MAXK; ++dt) {
    int ts = tt + dt - 5;
    if (ts < 0 || ts >= TREC) continue;
    __syncthreads();
    stageA(lds_a, resb + (size_t)(b * FREQ + ts) * SLICE + (size_t)v0 * 64, 64, tid);
    stageB(lds_b, Wc + dt * 4096, 64, tid);
    __syncthreads();
    mfma64(lds_a, lds_b, wid, lane, acc);
  }
  int lr = lane & 15, lg = lane >> 4;
  size_t so = (size_t)sl * SLICE;
#pragma unroll
  for (int mi = 0; mi < 4; ++mi)
#pragma unroll
    for (int ni = 0; ni < 4; ++ni) {
      int n = ni * 16 + lr;
      float bs = bsum[n];
#pragma unroll
      for (int r = 0; r < 4; ++r) {
        int m = wid * 64 + mi * 16 + lg * 4 + r;
        bf16 bv = (bf16)((acc[mi][ni][r] + bs) * (1.f / 6.f));
        xcN[so + (size_t)(v0 + m) * 64 + n] = bv;
        xcF[so + (size_t)n * 1024 + (v0 + m)] = bv;
      }
    }
}

// ---------------- inception (AR, last position) ----------------
__global__ __launch_bounds__(256) void incep_ar_k(const bf16* __restrict__ curb, int start,
                                                  const bf16* __restrict__ Wc,
                                                  const float* __restrict__ bsum,
                                                  bf16* __restrict__ ybN,
                                                  bf16* __restrict__ ybF) {
  __shared__ __align__(16) bf16 lds_a[256 * 72];
  __shared__ __align__(16) bf16 lds_b[64 * 72];
  int tid = threadIdx.x, wid = tid >> 6, lane = tid & 63;
  int v0 = blockIdx.x * 256;
  int b = blockIdx.y;
  f32x4 acc[4][4] = {};
  for (int j = 0; j < 6; ++j) {
    int slot = (start + 5 + j) % MAXK;
    __syncthreads();
    stageA(lds_a, curb + (size_t)(b * MAXK + slot) * SLICE + (size_t)v0 * 64, 64, tid);
    stageB(lds_b, Wc + j * 4096, 64, tid);
    __syncthreads();
    mfma64(lds_a, lds_b, wid, lane, acc);
  }
  int lr = lane & 15, lg = lane >> 4;
  size_t so = (size_t)b * SLICE;
#pragma unroll
  for (int mi = 0; mi < 4; ++mi)
#pragma unroll
    for (int ni = 0; ni < 4; ++ni) {
      int n = ni * 16 + lr;
      float bs = bsum[n];
#pragma unroll
      for (int r = 0; r < 4; ++r) {
        int m = wid * 64 + mi * 16 + lg * 4 + r;
        bf16 bv = (bf16)((acc[mi][ni][r] + bs) * (1.f / 6.f));
        ybN[so + (size_t)(v0 + m) * 64 + n] = bv;
        ybF[so + (size_t)n * 1024 + (v0 + m)] = bv;
      }
    }
}

// ---------------- mixprop hop: out = 0.05*X + 0.95*(A @ H) ----------------
__global__ __launch_bounds__(256) void prop_k(const bf16* __restrict__ A1,
                                              const bf16* __restrict__ A2,
                                              const bf16* __restrict__ inFa,
                                              const bf16* __restrict__ inFb,
                                              const bf16* __restrict__ xN,
                                              bf16* __restrict__ oNa, bf16* __restrict__ oFa,
                                              bf16* __restrict__ oNb, bf16* __restrict__ oFb) {
  __shared__ __align__(16) bf16 lds_a[256 * 72];
  __shared__ __align__(16) bf16 lds_b[64 * 72];
  int tid = threadIdx.x, wid = tid >> 6, lane = tid & 63;
  int v0 = blockIdx.x * 256;
  int sl = blockIdx.y;
  int za = blockIdx.z;
  const bf16* A = za ? A2 : A1;
  const bf16* inF = za ? inFb : inFa;
  bf16* oN = za ? oNb : oNa;
  bf16* oF = za ? oFb : oFa;
  f32x4 acc[4][4] = {};
  size_t so = (size_t)sl * SLICE;
  for (int k0 = 0; k0 < 1024; k0 += 64) {
    __syncthreads();
    stageA(lds_a, A + (size_t)v0 * 1024 + k0, 1024, tid);
    stageB(lds_b, inF + so + k0, 1024, tid);
    __syncthreads();
    mfma64(lds_a, lds_b, wid, lane, acc);
  }
  int lr = lane & 15, lg = lane >> 4;
#pragma unroll
  for (int mi = 0; mi < 4; ++mi)
#pragma unroll
    for (int ni = 0; ni < 4; ++ni) {
      int n = ni * 16 + lr;
#pragma unroll
      for (int r = 0; r < 4; ++r) {
        int m = wid * 64 + mi * 16 + lg * 4 + r;
        float x = (float)xN[so + (size_t)(v0 + m) * 64 + n];
        bf16 bv = (bf16)(0.05f * x + 0.95f * acc[mi][ni][r]);
        oN[so + (size_t)(v0 + m) * 64 + n] = bv;
        if (oF) oF[so + (size_t)n * 1024 + (v0 + m)] = bv;
      }
    }
}

// ---------------- gw projection (rec): acc = X + concat6 @ gwT + gbsum ----------------
__global__ __launch_bounds__(256) void gwacc_rec_k(Ptr6 hp, const bf16* __restrict__ gwT,
                                                   const float* __restrict__ gbsum,
                                                   const bf16* __restrict__ resb, int b0,
                                                   float* __restrict__ accR) {
  __shared__ __align__(16) bf16 lds_a[256 * 72];
  __shared__ __align__(16) bf16 lds_b[64 * 72];
  int tid = threadIdx.x, wid = tid >> 6, lane = tid & 63;
  int v0 = blockIdx.x * 256;
  int sl = blockIdx.y;
  int b = b0 + sl / TREC, tt = sl % TREC;
  f32x4 acc[4][4] = {};
  size_t so = (size_t)sl * SLICE;
  for (int j = 0; j < 6; ++j) {
    __syncthreads();
    stageA(lds_a, hp.p[j] + so + (size_t)v0 * 64, 64, tid);
    stageB(lds_b, gwT + j * 64, 384, tid);
    __syncthreads();
    mfma64(lds_a, lds_b, wid, lane, acc);
  }
  int lr = lane & 15, lg = lane >> 4;
  size_t xo = (size_t)(b * FREQ + tt) * SLICE;
#pragma unroll
  for (int mi = 0; mi < 4; ++mi)
#pragma unroll
    for (int ni = 0; ni < 4; ++ni) {
      int n = ni * 16 + lr;
      float gb = gbsum[n];
#pragma unroll
      for (int r = 0; r < 4; ++r) {
        int m = wid * 64 + mi * 16 + lg * 4 + r;
        float x = (float)resb[xo + (size_t)(v0 + m) * 64 + n];
        accR[so + (size_t)(v0 + m) * 64 + n] = x + acc[mi][ni][r] + gb;
      }
    }
}

// ---------------- gw projection (AR): cur[slotW] = cur[slotR] + concat6 @ gwT + gbsum ----------------
__global__ __launch_bounds__(256) void gwacc_ar_k(Ptr6 hp, const bf16* __restrict__ gwT,
                                                  const float* __restrict__ gbsum,
                                                  float* __restrict__ cur,
                                                  bf16* __restrict__ curb, int slotR,
                                                  int slotW) {
  __shared__ __align__(16) bf16 lds_a[256 * 72];
  __shared__ __align__(16) bf16 lds_b[64 * 72];
  int tid = threadIdx.x, wid = tid >> 6, lane = tid & 63;
  int v0 = blockIdx.x * 256;
  int b = blockIdx.y;
  f32x4 acc[4][4] = {};
  size_t so = (size_t)b * SLICE;
  for (int j = 0; j < 6; ++j) {
    __syncthreads();
    stageA(lds_a, hp.p[j] + so + (size_t)v0 * 64, 64, tid);
    stageB(lds_b, gwT + j * 64, 384, tid);
    __syncthreads();
    mfma64(lds_a, lds_b, wid, lane, acc);
  }
  int lr = lane & 15, lg = lane >> 4;
  size_t xo = ((size_t)b * MAXK + slotR) * SLICE;
  size_t wo = ((size_t)b * MAXK + slotW) * SLICE;
#pragma unroll
  for (int mi = 0; mi < 4; ++mi)
#pragma unroll
    for (int ni = 0; ni < 4; ++ni) {
      int n = ni * 16 + lr;
      float gb = gbsum[n];
#pragma unroll
      for (int r = 0; r < 4; ++r) {
        int m = wid * 64 + mi * 16 + lg * 4 + r;
        size_t o = (size_t)(v0 + m) * 64 + n;
        float val = cur[xo + o] + acc[mi][ni][r] + gb;
        cur[wo + o] = val;
        curb[wo + o] = (bf16)val;
      }
    }
}

// ---------------- decoder (rec) ----------------
__global__ __launch_bounds__(256) void dec_rec_k(const bf16* __restrict__ resb,
                                                 const float* __restrict__ accR, int b0,
                                                 const float* __restrict__ dw1,
                                                 const float* __restrict__ db1,
                                                 const float* __restrict__ dw2,
                                                 const float* __restrict__ db2,
                                                 float* __restrict__ outRec) {
  __shared__ __align__(16) float ins[64 * 68];
  __shared__ bf16 dw1s[64 * 128];
  __shared__ bf16 hs[64 * 132];
  __shared__ float dw2s[128 * 8];
  __shared__ float db1s[128], db2s[8];
  int t = threadIdx.x, v0 = blockIdx.x * 64;
  int sy = blockIdx.y;
  int bl = sy / FREQ, f = sy % FREQ;
  int b = b0 + bl;
  if (f == 0) {
    const bf16* src = resb + (size_t)(b * FREQ) * SLICE + (size_t)v0 * 64;
#pragma unroll
    for (int i = 0; i < 2; ++i) {
      int q = t + i * 256;
      int r = q >> 3, c = (q & 7) * 8;
      bf16 tmp[8];
      *(uint4*)tmp = *(const uint4*)&src[(size_t)r * 64 + c];
#pragma unroll
      for (int e = 0; e < 8; ++e) ins[r * 68 + c + e] = (float)tmp[e];
    }
  } else {
    const float* src = accR + (size_t)(bl * TREC + f - 1) * SLICE + (size_t)v0 * 64;
#pragma unroll
    for (int i = 0; i < 4; ++i) {
      int q = t + i * 256;
      int r = q >> 4, c = (q & 15) * 4;
      *(float4*)&ins[r * 68 + c] = *(const float4*)&src[(size_t)r * 64 + c];
    }
  }
#pragma unroll
  for (int i = 0; i < 32; ++i) {
    int q = t + i * 256;
    dw1s[q] = (bf16)dw1[q];
  }
#pragma unroll
  for (int i = 0; i < 4; ++i) {
    int q = t + i * 256;
    dw2s[q] = dw2[q];
  }
  if (t < 128) db1s[t] = db1[t];
  if (t < 8) db2s[t] = db2[t];
  __syncthreads();
  {
    int n = t & 63, jc = (t >> 6) * 32;
    for (int jj = 0; jj < 32; ++jj) {
      int j = jc + jj;
      float a = db1s[j];
#pragma unroll 16
      for (int k = 0; k < 64; ++k) a = fmaf(ins[n * 68 + k], (float)dw1s[k * 128 + j], a);
      hs[n * 132 + j] = (bf16)fmaxf(a, 0.f);
    }
  }
  __syncthreads();
  {
    int n = t & 63, sp = (t >> 6) * 2;
    for (int ss = 0; ss < 2; ++ss) {
      int s = sp + ss;
      float a = db2s[s];
#pragma unroll 16
      for (int j = 0; j < 128; ++j) a = fmaf((float)hs[n * 132 + j], dw2s[j * 8 + s], a);
      outRec[(size_t)b * 344064 + (size_t)(f * 8 + s) * 1024 + v0 + n] = a;
    }
  }
}

// ---------------- decoder (AR step) ----------------
__global__ __launch_bounds__(256) void dec_pred_k(const float* __restrict__ cur, int slot,
                                                  int step, const float* __restrict__ dw1,
                                                  const float* __restrict__ db1,
                                                  const float* __restrict__ dw2,
                                                  const float* __restrict__ db2,
                                                  float* __restrict__ outPred) {
  __shared__ __align__(16) float ins[64 * 68];
  __shared__ bf16 dw1s[64 * 128];
  __shared__ bf16 hs[64 * 132];
  __shared__ float dw2s[128 * 8];
  __shared__ float db1s[128], db2s[8];
  int t = threadIdx.x, v0 = blockIdx.x * 64;
  int b = blockIdx.y;
  const float* src = cur + ((size_t)b * MAXK + slot) * SLICE + (size_t)v0 * 64;
#pragma unroll
  for (int i = 0; i < 4; ++i) {
    int q = t + i * 256;
    int r = q >> 4, c = (q & 15) * 4;
    *(float4*)&ins[r * 68 + c] = *(const float4*)&src[(size_t)r * 64 + c];
  }
#pragma unroll
  for (int i = 0; i < 32; ++i) {
    int q = t + i * 256;
    dw1s[q] = (bf16)dw1[q];
  }
#pragma unroll
  for (int i = 0; i < 4; ++i) {
    int q = t + i * 256;
    dw2s[q] = dw2[q];
  }
  if (t < 128) db1s[t] = db1[t];
  if (t < 8) db2s[t] = db2[t];
  __syncthreads();
  {
    int n = t & 63, jc = (t >> 6) * 32;
    for (int jj = 0; jj < 32; ++jj) {
      int j = jc + jj;
      float a = db1s[j];
#pragma unroll 16
      for (int k = 0; k < 64; ++k) a = fmaf(ins[n * 68 + k], (float)dw1s[k * 128 + j], a);
      hs[n * 132 + j] = (bf16)fmaxf(a, 0.f);
    }
  }
  __syncthreads();
  {
    int n = t & 63, sp = (t >> 6) * 2;
    for (int ss = 0; ss < 2; ++ss) {
      int s = sp + ss;
      float a = db2s[s];
#pragma unroll 16
      for (int j = 0; j < 128; ++j) a = fmaf((float)hs[n * 132 + j], dw2s[j * 8 + s], a);
      outPred[(size_t)b * 98304 + (size_t)step * 8192 + (size_t)(v0 + n) * 8 + s] = a;
    }
  }
}

// ---------------- host launch ----------------
extern "C" void kernel_launch(void* const* d_in, const int* in_sizes, int n_in, void* d_out,
                              int out_size, void* d_ws, size_t ws_size, hipStream_t stream) {
  const float* x_diff = (const float*)d_in[0];
  const float* adj = (const float*)d_in[1];
  const float* enc_w1 = (const float*)d_in[2];
  const float* enc_b1 = (const float*)d_in[3];
  const float* enc_w2 = (const float*)d_in[4];
  const float* enc_b2 = (const float*)d_in[5];
  const float* dec_w1 = (const float*)d_in[6];
  const float* dec_b1 = (const float*)d_in[7];
  const float* dec_w2 = (const float*)d_in[8];
  const float* dec_b2 = (const float*)d_in[9];
  const float* g1_w = (const float*)d_in[10];
  const float* g1_b = (const float*)d_in[11];
  const float* g2_w = (const float*)d_in[12];
  const float* g2_b = (const float*)d_in[13];
  const float* cw[6];
  const float* cb_[6];
  for (int i = 0; i < 6; ++i) {
    cw[i] = (const float*)d_in[14 + 2 * i];
    cb_[i] = (const float*)d_in[15 + 2 * i];
  }

  char* base = (char*)d_ws;
  size_t off = 0;
  auto alloc = [&](size_t bytes) -> void* {
    void* p = base + off;
    off = (off + bytes + 255) & ~(size_t)255;
    return p;
  };
  float* adjT = (float*)alloc(1048576ULL * 4);
  float* rowsum = (float*)alloc(4096);
  float* colsum = (float*)alloc(4096);
  bf16* a1b = (bf16*)alloc(1048576ULL * 2);
  bf16* a2b = (bf16*)alloc(1048576ULL * 2);
  bf16* Wc = (bf16*)alloc(45056ULL * 2);
  float* bsum = (float*)alloc(256);
  bf16* gwT = (bf16*)alloc(24576ULL * 2);
  float* gbsum = (float*)alloc(256);
  bf16* resb = (bf16*)alloc((size_t)NB * FREQ * SLICE * 2);
  float* cur = (float*)alloc((size_t)NB * MAXK * SLICE * 4);
  bf16* curb = (bf16*)alloc((size_t)NB * MAXK * SLICE * 2);
  bf16* ybN = (bf16*)alloc((size_t)NB * SLICE * 2);
  bf16* ybF = (bf16*)alloc((size_t)NB * SLICE * 2);
  bf16* p1aN = (bf16*)alloc((size_t)NB * SLICE * 2);
  bf16* p1aF = (bf16*)alloc((size_t)NB * SLICE * 2);
  bf16* p1bN = (bf16*)alloc((size_t)NB * SLICE * 2);
  bf16* p1bF = (bf16*)alloc((size_t)NB * SLICE * 2);
  bf16* p2aN = (bf16*)alloc((size_t)NB * SLICE * 2);
  bf16* p2bN = (bf16*)alloc((size_t)NB * SLICE * 2);
  size_t fixedEnd = off;
  int cb = 8;
  while (cb > 1) {
    size_t S = (size_t)TREC * cb;
    size_t need = S * SLICE * 20 + 8192;
    if (fixedEnd + need <= ws_size) break;
    cb >>= 1;
  }
  size_t S = (size_t)TREC * cb;
  bf16* xcN = (bf16*)alloc(S * SLICE * 2);
  bf16* xcF = (bf16*)alloc(S * SLICE * 2);
  bf16* h1aN = (bf16*)alloc(S * SLICE * 2);
  bf16* h1aF = (bf16*)alloc(S * SLICE * 2);
  bf16* h1bN = (bf16*)alloc(S * SLICE * 2);
  bf16* h1bF = (bf16*)alloc(S * SLICE * 2);
  bf16* h2aN = (bf16*)alloc(S * SLICE * 2);
  bf16* h2bN = (bf16*)alloc(S * SLICE * 2);
  float* accR = (float*)alloc(S * SLICE * 4);

  float* outF = (float*)d_out;
  float* outRec = outF;
  float* outPred = outF + (size_t)2752512;

  transpose_k<<<dim3(32, 32), dim3(32, 8), 0, stream>>>(adj, adjT);
  rowsum_k<<<1024, 256, 0, stream>>>(adj, rowsum);
  rowsum_k<<<1024, 256, 0, stream>>>(adjT, colsum);
  norm_k<<<2048, 256, 0, stream>>>(adj, adjT, rowsum, colsum, a1b, a2b);
  combine_w_k<<<(MAXK * 4096 + 255) / 256, 256, 0, stream>>>(cw[0], cw[1], cw[2], cw[3], cw[4],
                                                             cw[5], cb_[0], cb_[1], cb_[2],
                                                             cb_[3], cb_[4], cb_[5], Wc, bsum);
  gwt_k<<<(64 * 384 + 255) / 256, 256, 0, stream>>>(g1_w, g2_w, g1_b, g2_b, gwT, gbsum);
  encoder_k<<<dim3(16, NB * FREQ), 256, 0, stream>>>(x_diff, enc_w1, enc_b1, enc_w2, enc_b2,
                                                     resb);
  curinit_k<<<(int)(((size_t)NB * MAXK * SLICE + 255) / 256), 256, 0, stream>>>(resb, cur,
                                                                                curb);

  for (int c0 = 0; c0 < NB; c0 += cb) {
    int Sg = TREC * cb;
    incep_k<<<dim3(4, Sg), 256, 0, stream>>>(resb, c0, Wc, bsum, xcN, xcF);
    prop_k<<<dim3(4, Sg, 2), 256, 0, stream>>>(a1b, a2b, xcF, xcF, xcN, h1aN, h1aF, h1bN,
                                               h1bF);
    prop_k<<<dim3(4, Sg, 2), 256, 0, stream>>>(a1b, a2b, h1aF, h1bF, xcN, h2aN, nullptr, h2bN,
                                               nullptr);
    Ptr6 hp;
    hp.p[0] = xcN; hp.p[1] = h1aN; hp.p[2] = h2aN;
    hp.p[3] = xcN; hp.p[4] = h1bN; hp.p[5] = h2bN;
    gwacc_rec_k<<<dim3(4, Sg), 256, 0, stream>>>(hp, gwT, gbsum, resb, c0, accR);
    dec_rec_k<<<dim3(16, cb * FREQ), 256, 0, stream>>>(resb, accR, c0, dec_w1, dec_b1, dec_w2,
                                                       dec_b2, outRec);
  }

  for (int s = 0; s < NSTEP; ++s) {
    int slotR = (s + 10) % MAXK;
    int slotW = s % MAXK;
    incep_ar_k<<<dim3(4, NB), 256, 0, stream>>>(curb, s, Wc, bsum, ybN, ybF);
    prop_k<<<dim3(4, NB, 2), 256, 0, stream>>>(a1b, a2b, ybF, ybF, ybN, p1aN, p1aF, p1bN,
                                               p1bF);
    prop_k<<<dim3(4, NB, 2), 256, 0, stream>>>(a1b, a2b, p1aF, p1bF, ybN, p2aN, nullptr, p2bN,
                                               nullptr);
    Ptr6 hp;
    hp.p[0] = ybN; hp.p[1] = p1aN; hp.p[2] = p2aN;
    hp.p[3] = ybN; hp.p[4] = p1bN; hp.p[5] = p2bN;
    gwacc_ar_k<<<dim3(4, NB), 256, 0, stream>>>(hp, gwT, gbsum, cur, curb, slotR, slotW);
    dec_pred_k<<<dim3(16, NB), 256, 0, stream>>>(cur, slotW, s, dec_w1, dec_b1, dec_w2, dec_b2,
                                                 outPred);
  }
}